// Round 1
// baseline (2038.051 us; speedup 1.0000x reference)
//
#include <hip/hip_runtime.h>
#include <math.h>

namespace {

constexpr int T  = 2048;
constexpr int D  = 1024;
constexpr int H  = 16;
constexpr int HD = 64;
constexpr int DL = 512;
constexpr float EPS   = 1.1920929e-07f;
constexpr float SCALE = 0.125f; // HD^-0.5

// ---------------------------------------------------------------------------
// proj_q: q[bh][t][0:64]  = rmsnorm(xh @ W_DQ^T @ W_UQ^T) * q_norm_w
//         q[bh][t][64:128]= (that) @ W_QR^T
// grid (T/64, B*H), block 256
// ---------------------------------------------------------------------------
__global__ __launch_bounds__(256) void proj_q_kernel(
    const float* __restrict__ x, const float* __restrict__ W_DQ,
    const float* __restrict__ W_UQ, const float* __restrict__ W_QR,
    const float* __restrict__ qnw, float* __restrict__ q)
{
  __shared__ float X[64][65];
  __shared__ float WD[64][65];
  __shared__ float WU[64][65];
  __shared__ float CQ[64][65];

  const int tid = threadIdx.x;
  const int bh  = blockIdx.y;
  const int t0  = blockIdx.x * 64;
  const int b   = bh >> 4, h = bh & 15;
  const int rg  = tid >> 4, c = tid & 15;
  const int r0  = rg * 4, c0 = c * 4;

#pragma unroll
  for (int i = 0; i < 16; ++i) {
    int idx = tid + i * 256;
    int r = idx >> 6, d0 = idx & 63;
    X[r][d0] = x[(size_t)(b * T + t0 + r) * D + h * HD + d0];
  }

  float acc[4][4] = {};
  for (int lc = 0; lc < 8; ++lc) {
    const int l0 = lc * 64;
    __syncthreads();
#pragma unroll
    for (int i = 0; i < 16; ++i) {
      int idx = tid + i * 256;
      int r = idx >> 6, d0 = idx & 63;
      WD[r][d0] = W_DQ[(size_t)(l0 + r) * HD + d0];
      WU[r][d0] = W_UQ[(size_t)r * DL + l0 + d0];
    }
    __syncthreads();
    float cq[4][4] = {};
    for (int d0 = 0; d0 < 64; ++d0) {
      float xa[4], wb[4];
#pragma unroll
      for (int i = 0; i < 4; ++i) xa[i] = X[r0 + i][d0];
#pragma unroll
      for (int j = 0; j < 4; ++j) wb[j] = WD[c0 + j][d0];
#pragma unroll
      for (int i = 0; i < 4; ++i)
#pragma unroll
        for (int j = 0; j < 4; ++j) cq[i][j] += xa[i] * wb[j];
    }
#pragma unroll
    for (int i = 0; i < 4; ++i)
#pragma unroll
      for (int j = 0; j < 4; ++j) CQ[r0 + i][c0 + j] = cq[i][j];
    __syncthreads();
    for (int lj = 0; lj < 64; ++lj) {
      float ca[4], wb[4];
#pragma unroll
      for (int i = 0; i < 4; ++i) ca[i] = CQ[r0 + i][lj];
#pragma unroll
      for (int j = 0; j < 4; ++j) wb[j] = WU[c0 + j][lj];
#pragma unroll
      for (int i = 0; i < 4; ++i)
#pragma unroll
        for (int j = 0; j < 4; ++j) acc[i][j] += ca[i] * wb[j];
    }
  }

  // RMS norm over HD=64 (16 col-threads hold the row)
  float w4[4];
#pragma unroll
  for (int j = 0; j < 4; ++j) w4[j] = qnw[c0 + j];
  float qn[4][4];
#pragma unroll
  for (int i = 0; i < 4; ++i) {
    float ss = acc[i][0] * acc[i][0] + acc[i][1] * acc[i][1] +
               acc[i][2] * acc[i][2] + acc[i][3] * acc[i][3];
    ss += __shfl_xor(ss, 1, 16);
    ss += __shfl_xor(ss, 2, 16);
    ss += __shfl_xor(ss, 4, 16);
    ss += __shfl_xor(ss, 8, 16);
    float inv = rsqrtf(ss * (1.0f / 64.0f) + EPS);
#pragma unroll
    for (int j = 0; j < 4; ++j) qn[i][j] = acc[i][j] * inv * w4[j];
  }

  // q_r = qn @ W_QR^T   (stage qn through CQ)
  __syncthreads();
#pragma unroll
  for (int i = 0; i < 4; ++i)
#pragma unroll
    for (int j = 0; j < 4; ++j) CQ[r0 + i][c0 + j] = qn[i][j];
#pragma unroll
  for (int i = 0; i < 16; ++i) {
    int idx = tid + i * 256;
    int r = idx >> 6, d0 = idx & 63;
    WD[r][d0] = W_QR[(size_t)r * HD + d0];
  }
  __syncthreads();
  float qr[4][4] = {};
  for (int d0 = 0; d0 < 64; ++d0) {
    float ca[4], wb[4];
#pragma unroll
    for (int i = 0; i < 4; ++i) ca[i] = CQ[r0 + i][d0];
#pragma unroll
    for (int j = 0; j < 4; ++j) wb[j] = WD[c0 + j][d0];
#pragma unroll
    for (int i = 0; i < 4; ++i)
#pragma unroll
      for (int j = 0; j < 4; ++j) qr[i][j] += ca[i] * wb[j];
  }

#pragma unroll
  for (int i = 0; i < 4; ++i) {
    size_t base = ((size_t)bh * T + t0 + r0 + i) * 128;
#pragma unroll
    for (int j = 0; j < 4; ++j) {
      q[base + c0 + j]      = qn[i][j];
      q[base + 64 + c0 + j] = qr[i][j];
    }
  }
}

// ---------------------------------------------------------------------------
// proj_kv: kv = (xh @ W_DKV^T) @ W_UKV^T   (128 wide)
//   k[...][0:64]  = rmsnorm(kv[:, :64]) * k_norm_w
//   k[...][64:128]= xh @ W_KR^T
//   v[...]        = kv[:, 64:]
// ---------------------------------------------------------------------------
__global__ __launch_bounds__(256) void proj_kv_kernel(
    const float* __restrict__ x, const float* __restrict__ W_DKV,
    const float* __restrict__ W_UKV, const float* __restrict__ W_KR,
    const float* __restrict__ knw, float* __restrict__ k, float* __restrict__ v)
{
  __shared__ float X[64][65];
  __shared__ float WD[64][65];
  __shared__ float CQ[64][65];
  __shared__ float WU[128][65];

  const int tid = threadIdx.x;
  const int bh  = blockIdx.y;
  const int t0  = blockIdx.x * 64;
  const int b   = bh >> 4, h = bh & 15;
  const int rg  = tid >> 4, c = tid & 15;
  const int r0  = rg * 4, c0 = c * 4;

#pragma unroll
  for (int i = 0; i < 16; ++i) {
    int idx = tid + i * 256;
    int r = idx >> 6, d0 = idx & 63;
    X[r][d0] = x[(size_t)(b * T + t0 + r) * D + h * HD + d0];
  }

  float acc[4][8] = {};
  for (int lc = 0; lc < 16; ++lc) {
    const int l0 = lc * 64;
    __syncthreads();
#pragma unroll
    for (int i = 0; i < 16; ++i) {
      int idx = tid + i * 256;
      int r = idx >> 6, d0 = idx & 63;
      WD[r][d0] = W_DKV[(size_t)(l0 + r) * HD + d0];
    }
#pragma unroll
    for (int i = 0; i < 32; ++i) {
      int idx = tid + i * 256;
      int r = idx >> 6, d0 = idx & 63; // r in [0,128)
      WU[r][d0] = W_UKV[(size_t)r * (2 * DL) + l0 + d0];
    }
    __syncthreads();
    float ck[4][4] = {};
    for (int d0 = 0; d0 < 64; ++d0) {
      float xa[4], wb[4];
#pragma unroll
      for (int i = 0; i < 4; ++i) xa[i] = X[r0 + i][d0];
#pragma unroll
      for (int j = 0; j < 4; ++j) wb[j] = WD[c0 + j][d0];
#pragma unroll
      for (int i = 0; i < 4; ++i)
#pragma unroll
        for (int j = 0; j < 4; ++j) ck[i][j] += xa[i] * wb[j];
    }
#pragma unroll
    for (int i = 0; i < 4; ++i)
#pragma unroll
      for (int j = 0; j < 4; ++j) CQ[r0 + i][c0 + j] = ck[i][j];
    __syncthreads();
    for (int lj = 0; lj < 64; ++lj) {
      float ca[4], wb[4], wb2[4];
#pragma unroll
      for (int i = 0; i < 4; ++i) ca[i] = CQ[r0 + i][lj];
#pragma unroll
      for (int j = 0; j < 4; ++j) wb[j]  = WU[c0 + j][lj];
#pragma unroll
      for (int j = 0; j < 4; ++j) wb2[j] = WU[64 + c0 + j][lj];
#pragma unroll
      for (int i = 0; i < 4; ++i)
#pragma unroll
        for (int j = 0; j < 4; ++j) {
          acc[i][j]     += ca[i] * wb[j];
          acc[i][4 + j] += ca[i] * wb2[j];
        }
    }
  }

  // k_c norm
  float w4[4];
#pragma unroll
  for (int j = 0; j < 4; ++j) w4[j] = knw[c0 + j];
  float kc[4][4];
#pragma unroll
  for (int i = 0; i < 4; ++i) {
    float ss = acc[i][0] * acc[i][0] + acc[i][1] * acc[i][1] +
               acc[i][2] * acc[i][2] + acc[i][3] * acc[i][3];
    ss += __shfl_xor(ss, 1, 16);
    ss += __shfl_xor(ss, 2, 16);
    ss += __shfl_xor(ss, 4, 16);
    ss += __shfl_xor(ss, 8, 16);
    float inv = rsqrtf(ss * (1.0f / 64.0f) + EPS);
#pragma unroll
    for (int j = 0; j < 4; ++j) kc[i][j] = acc[i][j] * inv * w4[j];
  }

  // v write (no norm)
#pragma unroll
  for (int i = 0; i < 4; ++i) {
    size_t vbase = ((size_t)bh * T + t0 + r0 + i) * 64;
#pragma unroll
    for (int j = 0; j < 4; ++j) v[vbase + c0 + j] = acc[i][4 + j];
  }

  // k_r = xh @ W_KR^T (X still resident)
  __syncthreads();
#pragma unroll
  for (int i = 0; i < 16; ++i) {
    int idx = tid + i * 256;
    int r = idx >> 6, d0 = idx & 63;
    WD[r][d0] = W_KR[(size_t)r * HD + d0];
  }
  __syncthreads();
  float kr[4][4] = {};
  for (int d0 = 0; d0 < 64; ++d0) {
    float ca[4], wb[4];
#pragma unroll
    for (int i = 0; i < 4; ++i) ca[i] = X[r0 + i][d0];
#pragma unroll
    for (int j = 0; j < 4; ++j) wb[j] = WD[c0 + j][d0];
#pragma unroll
    for (int i = 0; i < 4; ++i)
#pragma unroll
      for (int j = 0; j < 4; ++j) kr[i][j] += ca[i] * wb[j];
  }

#pragma unroll
  for (int i = 0; i < 4; ++i) {
    size_t base = ((size_t)bh * T + t0 + r0 + i) * 128;
#pragma unroll
    for (int j = 0; j < 4; ++j) {
      k[base + c0 + j]      = kc[i][j];
      k[base + 64 + c0 + j] = kr[i][j];
    }
  }
}

// ---------------------------------------------------------------------------
// attn: causal flash attention (d=128, dv=64) + fused out-proj W_O
// grid (T/64, B*H), block 256; thread = (rg, c) 16x16 grid of 4x4 microtiles
// ---------------------------------------------------------------------------
__global__ __launch_bounds__(256) void attn_kernel(
    const float* __restrict__ q, const float* __restrict__ k,
    const float* __restrict__ v, const float* __restrict__ W_O,
    float* __restrict__ out)
{
  __shared__ float Qs[64][129];
  __shared__ float Ks[64][129];
  __shared__ float Vs[64][68];
  __shared__ float Ps[64][68];

  const int tid = threadIdx.x;
  const int bh  = blockIdx.y;
  const int qt  = blockIdx.x;
  const int b   = bh >> 4, h = bh & 15;
  const int t0  = qt * 64;
  const int rg  = tid >> 4, c = tid & 15;
  const int r0  = rg * 4, c0 = c * 4;

#pragma unroll
  for (int i = 0; i < 32; ++i) {
    int idx = tid + i * 256;
    int r = idx >> 7, d0 = idx & 127;
    Qs[r][d0] = q[((size_t)bh * T + t0 + r) * 128 + d0];
  }

  float m[4], l[4], acc[4][4];
#pragma unroll
  for (int i = 0; i < 4; ++i) {
    m[i] = -INFINITY;
    l[i] = 0.0f;
#pragma unroll
    for (int j = 0; j < 4; ++j) acc[i][j] = 0.0f;
  }

  for (int jt = 0; jt <= qt; ++jt) {
    const int j0g = jt * 64;
    __syncthreads();
#pragma unroll
    for (int i = 0; i < 32; ++i) {
      int idx = tid + i * 256;
      int r = idx >> 7, d0 = idx & 127;
      Ks[r][d0] = k[((size_t)bh * T + j0g + r) * 128 + d0];
    }
#pragma unroll
    for (int i = 0; i < 16; ++i) {
      int idx = tid + i * 256;
      int r = idx >> 6, d0 = idx & 63;
      Vs[r][d0] = v[((size_t)bh * T + j0g + r) * 64 + d0];
    }
    __syncthreads();

    float s[4][4] = {};
    for (int d0 = 0; d0 < 128; ++d0) {
      float qa[4], kb[4];
#pragma unroll
      for (int i = 0; i < 4; ++i) qa[i] = Qs[r0 + i][d0];
#pragma unroll
      for (int j = 0; j < 4; ++j) kb[j] = Ks[c0 + j][d0];
#pragma unroll
      for (int i = 0; i < 4; ++i)
#pragma unroll
        for (int j = 0; j < 4; ++j) s[i][j] += qa[i] * kb[j];
    }

    const bool diag = (jt == qt);
    float p[4][4];
#pragma unroll
    for (int i = 0; i < 4; ++i) {
      float mx = -INFINITY;
#pragma unroll
      for (int j = 0; j < 4; ++j) {
        float sv = s[i][j] * SCALE;
        if (diag && (c0 + j > r0 + i)) sv = -INFINITY;
        s[i][j] = sv;
        mx = fmaxf(mx, sv);
      }
      mx = fmaxf(mx, __shfl_xor(mx, 1, 16));
      mx = fmaxf(mx, __shfl_xor(mx, 2, 16));
      mx = fmaxf(mx, __shfl_xor(mx, 4, 16));
      mx = fmaxf(mx, __shfl_xor(mx, 8, 16));
      const float mn  = fmaxf(m[i], mx);
      const float scl = __expf(m[i] - mn);
      float rsum = 0.0f;
#pragma unroll
      for (int j = 0; j < 4; ++j) {
        float pv = __expf(s[i][j] - mn);
        p[i][j] = pv;
        rsum += pv;
      }
      rsum += __shfl_xor(rsum, 1, 16);
      rsum += __shfl_xor(rsum, 2, 16);
      rsum += __shfl_xor(rsum, 4, 16);
      rsum += __shfl_xor(rsum, 8, 16);
      l[i] = l[i] * scl + rsum;
      m[i] = mn;
#pragma unroll
      for (int j = 0; j < 4; ++j) acc[i][j] *= scl;
    }

#pragma unroll
    for (int i = 0; i < 4; ++i)
#pragma unroll
      for (int j = 0; j < 4; ++j) Ps[r0 + i][c0 + j] = p[i][j];
    __syncthreads();

    for (int j0 = 0; j0 < 64; ++j0) {
      float pa[4], vb[4];
#pragma unroll
      for (int i = 0; i < 4; ++i) pa[i] = Ps[r0 + i][j0];
#pragma unroll
      for (int j = 0; j < 4; ++j) vb[j] = Vs[j0][c0 + j];
#pragma unroll
      for (int i = 0; i < 4; ++i)
#pragma unroll
        for (int j = 0; j < 4; ++j) acc[i][j] += pa[i] * vb[j];
    }
  }

  // epilogue: ctx = acc / l, out = ctx @ W_O^T
  __syncthreads();
#pragma unroll
  for (int i = 0; i < 4; ++i) {
    float invl = 1.0f / l[i];
#pragma unroll
    for (int j = 0; j < 4; ++j) Ps[r0 + i][c0 + j] = acc[i][j] * invl;
  }
#pragma unroll
  for (int i = 0; i < 16; ++i) {
    int idx = tid + i * 256;
    int r = idx >> 6, d0 = idx & 63;
    Vs[r][d0] = W_O[(size_t)r * HD + d0];
  }
  __syncthreads();
  float o[4][4] = {};
  for (int d0 = 0; d0 < 64; ++d0) {
    float ca[4], wb[4];
#pragma unroll
    for (int i = 0; i < 4; ++i) ca[i] = Ps[r0 + i][d0];
#pragma unroll
    for (int j = 0; j < 4; ++j) wb[j] = Vs[c0 + j][d0];
#pragma unroll
    for (int i = 0; i < 4; ++i)
#pragma unroll
      for (int j = 0; j < 4; ++j) o[i][j] += ca[i] * wb[j];
  }
#pragma unroll
  for (int i = 0; i < 4; ++i) {
    size_t base = (size_t)(b * T + t0 + r0 + i) * D + h * HD;
#pragma unroll
    for (int j = 0; j < 4; ++j) out[base + c0 + j] = o[i][j];
  }
}

} // namespace

extern "C" void kernel_launch(void* const* d_in, const int* in_sizes, int n_in,
                              void* d_out, int out_size, void* d_ws, size_t ws_size,
                              hipStream_t stream) {
  (void)in_sizes; (void)n_in; (void)out_size; (void)ws_size;
  const float* x     = (const float*)d_in[0];
  const float* W_DQ  = (const float*)d_in[1];
  const float* W_UQ  = (const float*)d_in[2];
  const float* W_DKV = (const float*)d_in[3];
  const float* W_UKV = (const float*)d_in[4];
  const float* W_QR  = (const float*)d_in[5];
  const float* W_KR  = (const float*)d_in[6];
  const float* W_O   = (const float*)d_in[7];
  const float* qnw   = (const float*)d_in[8];
  const float* knw   = (const float*)d_in[9];
  float* out = (float*)d_out;

  float* ws = (float*)d_ws;
  float* q  = ws;                       // 2*16*2048*128 = 8,388,608 floats
  float* k  = ws + (size_t)8388608;     // 8,388,608 floats
  float* v  = ws + (size_t)16777216;    // 4,194,304 floats

  dim3 grid(T / 64, 32); // (t-tiles, B*H)
  proj_q_kernel<<<grid, 256, 0, stream>>>(x, W_DQ, W_UQ, W_QR, qnw, q);
  proj_kv_kernel<<<grid, 256, 0, stream>>>(x, W_DKV, W_UKV, W_KR, knw, k, v);
  attn_kernel<<<grid, 256, 0, stream>>>(q, k, v, W_O, out);
}

// Round 2
// 290.738 us; speedup vs baseline: 7.0099x; 7.0099x over previous
//
#include <hip/hip_runtime.h>
#include <math.h>

namespace {

constexpr int T  = 2048;
constexpr int HD = 64;
constexpr float EPS   = 1.1920929e-07f;
constexpr float SCALE = 0.125f; // HD^-0.5

// bf16 weight pool offsets (in elements)
constexpr int OFF_DQ  = 0;       // 512*64
constexpr int OFF_UQ  = 32768;   // 64*512
constexpr int OFF_DKV = 65536;   // 1024*64
constexpr int OFF_UKV = 131072;  // 128*1024
constexpr int OFF_QR  = 262144;  // 64*64
constexpr int OFF_KR  = 266240;  // 64*64
constexpr int OFF_O   = 270336;  // 64*64
constexpr int W_TOTAL = 274432;

typedef __attribute__((ext_vector_type(8))) short bf8v;  // 8 bf16 (4 VGPR)
typedef __attribute__((ext_vector_type(4))) float f4v;   // MFMA C/D

#define MFMA16(a, b, c) __builtin_amdgcn_mfma_f32_16x16x32_bf16((a), (b), (c), 0, 0, 0)

__device__ __forceinline__ short f2bf(float f) {
  union { float f; unsigned u; } v; v.f = f;
  unsigned r = v.u + 0x7FFFu + ((v.u >> 16) & 1u); // RNE
  return (short)(r >> 16);
}

__device__ __forceinline__ f4v z4() { f4v z = {0.f, 0.f, 0.f, 0.f}; return z; }

// XOR swizzles: spread row-strided b128 accesses across banks (m214 pattern)
__device__ __forceinline__ int swz128(int b) { return b ^ (((b >> 7) & 7) << 4); }
__device__ __forceinline__ int swz256(int b) { return b ^ (((b >> 8) & 7) << 4); }

__device__ __forceinline__ bf8v ldA128(const short* lds, int row, int k) {
  return *(const bf8v*)((const char*)lds + swz128(row * 128 + k * 2));
}
__device__ __forceinline__ bf8v ldA256(const short* lds, int row, int k) {
  return *(const bf8v*)((const char*)lds + swz256(row * 256 + k * 2));
}

// stage a row-major 64x64 bf16 tile (src row stride = stride elems) into swizzled LDS
__device__ __forceinline__ void stage64x64(short* lds, const short* src, int stride, int tid) {
#pragma unroll
  for (int p = 0; p < 2; ++p) {
    int ci = tid + p * 256;
    int r = ci >> 3, c = (ci & 7) << 3;
    bf8v v = *(const bf8v*)(src + (size_t)r * stride + c);
    *(bf8v*)((char*)lds + swz128(ci * 16)) = v;
  }
}
__device__ __forceinline__ void stage128x64(short* lds, const short* src, int stride, int tid) {
#pragma unroll
  for (int p = 0; p < 4; ++p) {
    int ci = tid + p * 256;
    int r = ci >> 3, c = (ci & 7) << 3;
    bf8v v = *(const bf8v*)(src + (size_t)r * stride + c);
    *(bf8v*)((char*)lds + swz128(ci * 16)) = v;
  }
}

// scatter a 16x16 D-fragment (col=lane&15, row=(lane>>4)*4+r) as bf16 into LDS
__device__ __forceinline__ void scat128(short* lds, int row0, int lane, int nt, f4v v) {
  int col = nt * 16 + (lane & 15);
  int r0 = row0 + ((lane >> 4) << 2);
#pragma unroll
  for (int r = 0; r < 4; ++r)
    *(short*)((char*)lds + swz128((r0 + r) * 128 + col * 2)) = f2bf(v[r]);
}
__device__ __forceinline__ void scat256(short* lds, int row0, int lane, int col, f4v v) {
  int r0 = row0 + ((lane >> 4) << 2);
#pragma unroll
  for (int r = 0; r < 4; ++r)
    *(short*)((char*)lds + swz256((r0 + r) * 256 + col * 2)) = f2bf(v[r]);
}

// ---------------------------------------------------------------------------
// conversions
// ---------------------------------------------------------------------------
__global__ __launch_bounds__(256) void cvt_x_kernel(const float* __restrict__ x,
                                                    short* __restrict__ xb) {
  int i = (blockIdx.x * 256 + threadIdx.x) * 4; // over x linear (B,T,D)
  float4 v = *(const float4*)(x + i);
  int d = i & 1023, t = (i >> 10) & 2047, b = i >> 21;
  int h = d >> 6, dd = d & 63;
  short4 o;
  o.x = f2bf(v.x); o.y = f2bf(v.y); o.z = f2bf(v.z); o.w = f2bf(v.w);
  *(short4*)(xb + ((((size_t)b * 16 + h) * T + t) * 64 + dd)) = o;
}

__global__ __launch_bounds__(256) void cvt_w_kernel(
    const float* __restrict__ W_DQ, const float* __restrict__ W_UQ,
    const float* __restrict__ W_DKV, const float* __restrict__ W_UKV,
    const float* __restrict__ W_QR, const float* __restrict__ W_KR,
    const float* __restrict__ W_O, short* __restrict__ wb) {
  int i = blockIdx.x * 256 + threadIdx.x;
  const float* src; int off;
  if      (i < 32768)  { src = W_DQ;  off = 0; }
  else if (i < 65536)  { src = W_UQ;  off = 32768; }
  else if (i < 131072) { src = W_DKV; off = 65536; }
  else if (i < 262144) { src = W_UKV; off = 131072; }
  else if (i < 266240) { src = W_QR;  off = 262144; }
  else if (i < 270336) { src = W_KR;  off = 266240; }
  else                 { src = W_O;   off = 270336; }
  wb[i] = f2bf(src[i - off]);
}

// ---------------------------------------------------------------------------
// proj_q: q[bh][t][0:64]=rmsnorm((xh WDQ^T) WUQ^T)*qnw ; [64:128]= that @ WQR^T
// grid (32, 32), block 256 (4 waves, wave w owns rows w*16..w*16+15)
// ---------------------------------------------------------------------------
__global__ __launch_bounds__(256) void proj_q_mfma(
    const short* __restrict__ xb, const short* __restrict__ wb,
    const float* __restrict__ qnw, short* __restrict__ qb) {
  __shared__ __attribute__((aligned(16))) short Xs[64 * 64];
  __shared__ __attribute__((aligned(16))) short Wd[64 * 64];
  __shared__ __attribute__((aligned(16))) short Wu[64 * 64];
  __shared__ __attribute__((aligned(16))) short Cs[64 * 64];
  __shared__ __attribute__((aligned(16))) short Qr[64 * 64];

  const int tid = threadIdx.x, lane = tid & 63, w = tid >> 6;
  const int bh = blockIdx.y, t0 = blockIdx.x * 64;
  const int arow = w * 16 + (lane & 15);
  const int koff = (lane >> 4) << 3;

  stage64x64(Xs, xb + ((size_t)bh * T + t0) * 64, 64, tid);

  f4v acc[4];
#pragma unroll
  for (int nt = 0; nt < 4; ++nt) acc[nt] = z4();

  for (int lc = 0; lc < 8; ++lc) {
    const int l0 = lc * 64;
    __syncthreads();
    stage64x64(Wd, wb + OFF_DQ + (size_t)l0 * 64, 64, tid); // B1[n][k]=W_DQ[l0+n][k]
    stage64x64(Wu, wb + OFF_UQ + l0, 512, tid);             // B2[n][k]=W_UQ[n][l0+k]
    __syncthreads();
    f4v cc[4];
#pragma unroll
    for (int nt = 0; nt < 4; ++nt) cc[nt] = z4();
#pragma unroll
    for (int ks = 0; ks < 2; ++ks) {
      bf8v a = ldA128(Xs, arow, ks * 32 + koff);
#pragma unroll
      for (int nt = 0; nt < 4; ++nt) {
        bf8v b = ldA128(Wd, nt * 16 + (lane & 15), ks * 32 + koff);
        cc[nt] = MFMA16(a, b, cc[nt]);
      }
    }
#pragma unroll
    for (int nt = 0; nt < 4; ++nt) scat128(Cs, w * 16, lane, nt, cc[nt]); // own rows
#pragma unroll
    for (int ks = 0; ks < 2; ++ks) {
      bf8v a = ldA128(Cs, arow, ks * 32 + koff);
#pragma unroll
      for (int nt = 0; nt < 4; ++nt) {
        bf8v b = ldA128(Wu, nt * 16 + (lane & 15), ks * 32 + koff);
        acc[nt] = MFMA16(a, b, acc[nt]);
      }
    }
  }

  // RMS norm: lane's 4 rows = w*16 + (lane>>4)*4 + r, cols nt*16+(lane&15)
  float w4[4];
#pragma unroll
  for (int nt = 0; nt < 4; ++nt) w4[nt] = qnw[nt * 16 + (lane & 15)];
  f4v qn[4];
#pragma unroll
  for (int r = 0; r < 4; ++r) {
    float ss = 0.f;
#pragma unroll
    for (int nt = 0; nt < 4; ++nt) ss += acc[nt][r] * acc[nt][r];
    ss += __shfl_xor(ss, 1, 16); ss += __shfl_xor(ss, 2, 16);
    ss += __shfl_xor(ss, 4, 16); ss += __shfl_xor(ss, 8, 16);
    float inv = rsqrtf(ss * (1.f / 64.f) + EPS);
#pragma unroll
    for (int nt = 0; nt < 4; ++nt) qn[nt][r] = acc[nt][r] * inv * w4[nt];
  }

  __syncthreads(); // all GEMM1 reads of Wd done
#pragma unroll
  for (int nt = 0; nt < 4; ++nt) scat128(Cs, w * 16, lane, nt, qn[nt]);
  stage64x64(Wd, wb + OFF_QR, 64, tid);
  __syncthreads();

  f4v qr[4];
#pragma unroll
  for (int nt = 0; nt < 4; ++nt) qr[nt] = z4();
#pragma unroll
  for (int ks = 0; ks < 2; ++ks) {
    bf8v a = ldA128(Cs, arow, ks * 32 + koff);
#pragma unroll
    for (int nt = 0; nt < 4; ++nt) {
      bf8v b = ldA128(Wd, nt * 16 + (lane & 15), ks * 32 + koff);
      qr[nt] = MFMA16(a, b, qr[nt]);
    }
  }
#pragma unroll
  for (int nt = 0; nt < 4; ++nt) scat128(Qr, w * 16, lane, nt, qr[nt]);
  __syncthreads();

  short* qdst = qb + ((size_t)bh * T + t0) * 128;
#pragma unroll
  for (int p = 0; p < 2; ++p) {
    int ci = tid + p * 256;
    int r = ci >> 3, c = (ci & 7) << 3;
    *(bf8v*)(qdst + (size_t)r * 128 + c) =
        *(const bf8v*)((const char*)Cs + swz128(ci * 16));
    *(bf8v*)(qdst + (size_t)r * 128 + 64 + c) =
        *(const bf8v*)((const char*)Qr + swz128(ci * 16));
  }
}

// ---------------------------------------------------------------------------
// proj_kv: kv=(xh WDKV^T) WUKV^T (128 wide); k=[rms(kv[:,:64])*knw, xh WKR^T];
// vt[bh][d][t] = kv[:,64:]^T
// ---------------------------------------------------------------------------
__global__ __launch_bounds__(256) void proj_kv_mfma(
    const short* __restrict__ xb, const short* __restrict__ wb,
    const float* __restrict__ knw, short* __restrict__ kb, short* __restrict__ vtg) {
  __shared__ __attribute__((aligned(16))) short Xs[64 * 64];
  __shared__ __attribute__((aligned(16))) short Wd[64 * 64];
  __shared__ __attribute__((aligned(16))) short Cs[64 * 64];
  __shared__ __attribute__((aligned(16))) short Wu[128 * 64];
  __shared__ __attribute__((aligned(16))) short Ko[64 * 128]; // 256B rows
  __shared__ __attribute__((aligned(16))) short Vt[64 * 64];  // [d][t_local]

  const int tid = threadIdx.x, lane = tid & 63, w = tid >> 6;
  const int bh = blockIdx.y, t0 = blockIdx.x * 64;
  const int arow = w * 16 + (lane & 15);
  const int koff = (lane >> 4) << 3;

  stage64x64(Xs, xb + ((size_t)bh * T + t0) * 64, 64, tid);

  f4v acc[8];
#pragma unroll
  for (int nt = 0; nt < 8; ++nt) acc[nt] = z4();

  for (int lc = 0; lc < 16; ++lc) {
    const int l0 = lc * 64;
    __syncthreads();
    stage64x64(Wd, wb + OFF_DKV + (size_t)l0 * 64, 64, tid);
    stage128x64(Wu, wb + OFF_UKV + l0, 1024, tid);
    __syncthreads();
    f4v cc[4];
#pragma unroll
    for (int nt = 0; nt < 4; ++nt) cc[nt] = z4();
#pragma unroll
    for (int ks = 0; ks < 2; ++ks) {
      bf8v a = ldA128(Xs, arow, ks * 32 + koff);
#pragma unroll
      for (int nt = 0; nt < 4; ++nt) {
        bf8v b = ldA128(Wd, nt * 16 + (lane & 15), ks * 32 + koff);
        cc[nt] = MFMA16(a, b, cc[nt]);
      }
    }
#pragma unroll
    for (int nt = 0; nt < 4; ++nt) scat128(Cs, w * 16, lane, nt, cc[nt]);
#pragma unroll
    for (int ks = 0; ks < 2; ++ks) {
      bf8v a = ldA128(Cs, arow, ks * 32 + koff);
#pragma unroll
      for (int nt = 0; nt < 8; ++nt) {
        bf8v b = ldA128(Wu, nt * 16 + (lane & 15), ks * 32 + koff);
        acc[nt] = MFMA16(a, b, acc[nt]);
      }
    }
  }

  // k_c norm on acc[0..3]
  float w4[4];
#pragma unroll
  for (int nt = 0; nt < 4; ++nt) w4[nt] = knw[nt * 16 + (lane & 15)];
#pragma unroll
  for (int r = 0; r < 4; ++r) {
    float ss = 0.f;
#pragma unroll
    for (int nt = 0; nt < 4; ++nt) ss += acc[nt][r] * acc[nt][r];
    ss += __shfl_xor(ss, 1, 16); ss += __shfl_xor(ss, 2, 16);
    ss += __shfl_xor(ss, 4, 16); ss += __shfl_xor(ss, 8, 16);
    float inv = rsqrtf(ss * (1.f / 64.f) + EPS);
#pragma unroll
    for (int nt = 0; nt < 4; ++nt) acc[nt][r] *= inv * w4[nt];
  }
#pragma unroll
  for (int nt = 0; nt < 4; ++nt) scat256(Ko, w * 16, lane, nt * 16 + (lane & 15), acc[nt]);
  // v transposed into Vt[d][t_local]
#pragma unroll
  for (int nt = 0; nt < 4; ++nt) {
    int d = nt * 16 + (lane & 15);
    int tl0 = w * 16 + ((lane >> 4) << 2);
#pragma unroll
    for (int r = 0; r < 4; ++r)
      *(short*)((char*)Vt + swz128(d * 128 + (tl0 + r) * 2)) = f2bf(acc[4 + nt][r]);
  }

  __syncthreads();
  stage64x64(Wd, wb + OFF_KR, 64, tid);
  __syncthreads();
  f4v kr[4];
#pragma unroll
  for (int nt = 0; nt < 4; ++nt) kr[nt] = z4();
#pragma unroll
  for (int ks = 0; ks < 2; ++ks) {
    bf8v a = ldA128(Xs, arow, ks * 32 + koff);
#pragma unroll
    for (int nt = 0; nt < 4; ++nt) {
      bf8v b = ldA128(Wd, nt * 16 + (lane & 15), ks * 32 + koff);
      kr[nt] = MFMA16(a, b, kr[nt]);
    }
  }
#pragma unroll
  for (int nt = 0; nt < 4; ++nt) scat256(Ko, w * 16, lane, 64 + nt * 16 + (lane & 15), kr[nt]);
  __syncthreads();

  short* kdst = kb + ((size_t)bh * T + t0) * 128;
#pragma unroll
  for (int p = 0; p < 4; ++p) {
    int ci = tid + p * 256;
    int r = ci >> 4, c = (ci & 15) << 3;
    *(bf8v*)(kdst + (size_t)r * 128 + c) =
        *(const bf8v*)((const char*)Ko + swz256(ci * 16));
  }
#pragma unroll
  for (int p = 0; p < 2; ++p) {
    int ci = tid + p * 256;
    int d = ci >> 3, c = (ci & 7) << 3;
    *(bf8v*)(vtg + ((size_t)bh * 64 + d) * T + t0 + c) =
        *(const bf8v*)((const char*)Vt + swz128(ci * 16));
  }
}

// ---------------------------------------------------------------------------
// attn: causal flash attention (d=128, dv=64), MFMA, fused W_O epilogue
// ---------------------------------------------------------------------------
__global__ __launch_bounds__(256) void attn_mfma(
    const short* __restrict__ qb, const short* __restrict__ kb,
    const short* __restrict__ vtg, const short* __restrict__ wb,
    float* __restrict__ out) {
  __shared__ __attribute__((aligned(16))) short Ks[64 * 128]; // 256B rows, swz256
  __shared__ __attribute__((aligned(16))) short Ps[64 * 64];  // 128B rows, swz128

  const int tid = threadIdx.x, lane = tid & 63, w = tid >> 6;
  const int bh = blockIdx.y, qt = blockIdx.x;
  const int b = bh >> 4, h = bh & 15;
  const int t0 = qt * 64;
  const int koff = (lane >> 4) << 3;
  const int lrow = w * 16 + ((lane >> 4) << 2); // first of lane's 4 local rows

  // Q fragments, rows t0 + w*16 + (lane&15), full k=128
  bf8v aq[4];
  {
    const short* qsrc = qb + ((size_t)bh * T + t0 + w * 16 + (lane & 15)) * 128;
#pragma unroll
    for (int ks = 0; ks < 4; ++ks)
      aq[ks] = *(const bf8v*)(qsrc + ks * 32 + koff);
  }

  f4v ctx[4];
  float m[4], l[4];
#pragma unroll
  for (int nt = 0; nt < 4; ++nt) ctx[nt] = z4();
#pragma unroll
  for (int r = 0; r < 4; ++r) { m[r] = -INFINITY; l[r] = 0.f; }

  const short* vbase = vtg + (size_t)bh * 64 * T;

  for (int jt = 0; jt <= qt; ++jt) {
    const int j0 = jt * 64;
    __syncthreads();
    {
      const short* ksrc = kb + ((size_t)bh * T + j0) * 128;
#pragma unroll
      for (int p = 0; p < 4; ++p) {
        int ci = tid + p * 256;
        bf8v v = *(const bf8v*)(ksrc + ci * 8);
        *(bf8v*)((char*)Ks + swz256(ci * 16)) = v;
      }
    }
    __syncthreads();

    f4v s[4];
#pragma unroll
    for (int nt = 0; nt < 4; ++nt) s[nt] = z4();
#pragma unroll
    for (int ks = 0; ks < 4; ++ks) {
#pragma unroll
      for (int nt = 0; nt < 4; ++nt) {
        bf8v bk = ldA256(Ks, nt * 16 + (lane & 15), ks * 32 + koff);
        s[nt] = MFMA16(aq[ks], bk, s[nt]);
      }
    }

    const bool diag = (jt == qt);
#pragma unroll
    for (int r = 0; r < 4; ++r) {
      const int grow = t0 + lrow + r;
      float sv[4];
#pragma unroll
      for (int nt = 0; nt < 4; ++nt) {
        float xv = s[nt][r] * SCALE;
        if (diag && (j0 + nt * 16 + (lane & 15) > grow)) xv = -INFINITY;
        sv[nt] = xv;
      }
      float mx = fmaxf(fmaxf(sv[0], sv[1]), fmaxf(sv[2], sv[3]));
      mx = fmaxf(mx, __shfl_xor(mx, 1, 16)); mx = fmaxf(mx, __shfl_xor(mx, 2, 16));
      mx = fmaxf(mx, __shfl_xor(mx, 4, 16)); mx = fmaxf(mx, __shfl_xor(mx, 8, 16));
      const float mn  = fmaxf(m[r], mx);
      const float scl = __expf(m[r] - mn);
      float rs = 0.f, p4[4];
#pragma unroll
      for (int nt = 0; nt < 4; ++nt) { p4[nt] = __expf(sv[nt] - mn); rs += p4[nt]; }
      rs += __shfl_xor(rs, 1, 16); rs += __shfl_xor(rs, 2, 16);
      rs += __shfl_xor(rs, 4, 16); rs += __shfl_xor(rs, 8, 16);
      l[r] = l[r] * scl + rs; m[r] = mn;
#pragma unroll
      for (int nt = 0; nt < 4; ++nt) {
        ctx[nt][r] *= scl;
        *(short*)((char*)Ps + swz128((lrow + r) * 128 + (nt * 16 + (lane & 15)) * 2)) =
            f2bf(p4[nt]);
      }
    }

    // PV: A = P (own rows), B[n=d][k=t] = vt rows (contiguous)
#pragma unroll
    for (int ks = 0; ks < 2; ++ks) {
      bf8v pa = ldA128(Ps, w * 16 + (lane & 15), ks * 32 + koff);
#pragma unroll
      for (int nt = 0; nt < 4; ++nt) {
        bf8v vb = *(const bf8v*)(vbase + (size_t)(nt * 16 + (lane & 15)) * T +
                                 j0 + ks * 32 + koff);
        ctx[nt] = MFMA16(pa, vb, ctx[nt]);
      }
    }
  }

  // epilogue: ctx/l  -> Ps (bf16), W_O -> Ks (as 128B-row tile), out-proj
  f4v cn[4];
#pragma unroll
  for (int nt = 0; nt < 4; ++nt) {
#pragma unroll
    for (int r = 0; r < 4; ++r) cn[nt][r] = ctx[nt][r] / l[r];
  }
  __syncthreads(); // all Ks reads done before overwrite
#pragma unroll
  for (int nt = 0; nt < 4; ++nt) scat128(Ps, w * 16, lane, nt, cn[nt]);
  stage64x64(Ks, wb + OFF_O, 64, tid);
  __syncthreads();

  f4v o[4];
#pragma unroll
  for (int nt = 0; nt < 4; ++nt) o[nt] = z4();
#pragma unroll
  for (int ks = 0; ks < 2; ++ks) {
    bf8v a = ldA128(Ps, w * 16 + (lane & 15), ks * 32 + koff);
#pragma unroll
    for (int nt = 0; nt < 4; ++nt) {
      bf8v bw = ldA128(Ks, nt * 16 + (lane & 15), ks * 32 + koff);
      o[nt] = MFMA16(a, bw, o[nt]);
    }
  }

  float* obase = out + (size_t)b * T * 1024 + h * 64;
#pragma unroll
  for (int nt = 0; nt < 4; ++nt) {
#pragma unroll
    for (int r = 0; r < 4; ++r)
      obase[(size_t)(t0 + lrow + r) * 1024 + nt * 16 + (lane & 15)] = o[nt][r];
  }
}

} // namespace

extern "C" void kernel_launch(void* const* d_in, const int* in_sizes, int n_in,
                              void* d_out, int out_size, void* d_ws, size_t ws_size,
                              hipStream_t stream) {
  (void)in_sizes; (void)n_in; (void)out_size; (void)ws_size;
  const float* x     = (const float*)d_in[0];
  const float* W_DQ  = (const float*)d_in[1];
  const float* W_UQ  = (const float*)d_in[2];
  const float* W_DKV = (const float*)d_in[3];
  const float* W_UKV = (const float*)d_in[4];
  const float* W_QR  = (const float*)d_in[5];
  const float* W_KR  = (const float*)d_in[6];
  const float* W_O   = (const float*)d_in[7];
  const float* qnw   = (const float*)d_in[8];
  const float* knw   = (const float*)d_in[9];
  float* out = (float*)d_out;

  short* ws = (short*)d_ws;
  short* xb  = ws;                          // 4,194,304
  short* qb  = ws + (size_t)4194304;        // 8,388,608
  short* kb  = ws + (size_t)12582912;       // 8,388,608
  short* vtg = ws + (size_t)20971520;       // 4,194,304
  short* wb  = ws + (size_t)25165824;       // 274,432

  cvt_x_kernel<<<4096, 256, 0, stream>>>(x, xb);
  cvt_w_kernel<<<W_TOTAL / 256, 256, 0, stream>>>(W_DQ, W_UQ, W_DKV, W_UKV,
                                                  W_QR, W_KR, W_O, wb);
  dim3 grid(T / 64, 32);
  proj_q_mfma<<<grid, 256, 0, stream>>>(xb, wb, qnw, qb);
  proj_kv_mfma<<<grid, 256, 0, stream>>>(xb, wb, knw, kb, vtg);
  attn_mfma<<<grid, 256, 0, stream>>>(qb, kb, vtg, wb, out);
}

// Round 3
// 169.582 us; speedup vs baseline: 12.0181x; 1.7144x over previous
//
#include <hip/hip_runtime.h>
#include <math.h>

namespace {

constexpr int T  = 2048;
constexpr int HD = 64;
constexpr float EPS   = 1.1920929e-07f;
constexpr float SCALE = 0.125f; // HD^-0.5

// bf16 weight pool offsets (in elements)
constexpr int OFF_DQ  = 0;       // 512*64
constexpr int OFF_UQ  = 32768;   // 64*512
constexpr int OFF_DKV = 65536;   // 1024*64
constexpr int OFF_UKV = 131072;  // 128*1024
constexpr int OFF_QR  = 262144;  // 64*64
constexpr int OFF_KR  = 266240;  // 64*64
constexpr int OFF_O   = 270336;  // 64*64
constexpr int W_TOTAL = 274432;

typedef __attribute__((ext_vector_type(8))) short bf8v;  // 8 bf16 (4 VGPR)
typedef __attribute__((ext_vector_type(4))) float f4v;   // MFMA C/D

#define MFMA16(a, b, c) __builtin_amdgcn_mfma_f32_16x16x32_bf16((a), (b), (c), 0, 0, 0)

__device__ __forceinline__ short f2bf(float f) {
  union { float f; unsigned u; } v; v.f = f;
  unsigned r = v.u + 0x7FFFu + ((v.u >> 16) & 1u); // RNE
  return (short)(r >> 16);
}

__device__ __forceinline__ f4v z4() { f4v z = {0.f, 0.f, 0.f, 0.f}; return z; }

// XOR swizzles: spread row-strided b128 accesses across banks (m214 pattern)
__device__ __forceinline__ int swz128(int b) { return b ^ (((b >> 7) & 7) << 4); }
__device__ __forceinline__ int swz256(int b) { return b ^ (((b >> 8) & 7) << 4); }

__device__ __forceinline__ bf8v ldA128(const short* lds, int row, int k) {
  return *(const bf8v*)((const char*)lds + swz128(row * 128 + k * 2));
}
__device__ __forceinline__ bf8v ldA256(const short* lds, int row, int k) {
  return *(const bf8v*)((const char*)lds + swz256(row * 256 + k * 2));
}

// stage a row-major 64x64 bf16 tile (src row stride = stride elems) into swizzled LDS
__device__ __forceinline__ void stage64x64(short* lds, const short* src, int stride, int tid) {
#pragma unroll
  for (int p = 0; p < 2; ++p) {
    int ci = tid + p * 256;
    int r = ci >> 3, c = (ci & 7) << 3;
    bf8v v = *(const bf8v*)(src + (size_t)r * stride + c);
    *(bf8v*)((char*)lds + swz128(ci * 16)) = v;
  }
}
__device__ __forceinline__ void stage128x64(short* lds, const short* src, int stride, int tid) {
#pragma unroll
  for (int p = 0; p < 4; ++p) {
    int ci = tid + p * 256;
    int r = ci >> 3, c = (ci & 7) << 3;
    bf8v v = *(const bf8v*)(src + (size_t)r * stride + c);
    *(bf8v*)((char*)lds + swz128(ci * 16)) = v;
  }
}

// scatter a 16x16 D-fragment (col=lane&15, row=(lane>>4)*4+r) as bf16 into LDS
__device__ __forceinline__ void scat128(short* lds, int row0, int lane, int nt, f4v v) {
  int col = nt * 16 + (lane & 15);
  int r0 = row0 + ((lane >> 4) << 2);
#pragma unroll
  for (int r = 0; r < 4; ++r)
    *(short*)((char*)lds + swz128((r0 + r) * 128 + col * 2)) = f2bf(v[r]);
}
__device__ __forceinline__ void scat256(short* lds, int row0, int lane, int col, f4v v) {
  int r0 = row0 + ((lane >> 4) << 2);
#pragma unroll
  for (int r = 0; r < 4; ++r)
    *(short*)((char*)lds + swz256((r0 + r) * 256 + col * 2)) = f2bf(v[r]);
}

// async global->LDS, 16B per lane; LDS dest wave-uniform base + lane*16
__device__ __forceinline__ void gload_lds16(const void* g, void* l) {
  __builtin_amdgcn_global_load_lds(
      (const __attribute__((address_space(1))) void*)g,
      (__attribute__((address_space(3))) void*)l, 16, 0, 0);
}

// DPP 16-lane row reductions (quad_perm swaps + mirrors) — full-rate VALU
__device__ __forceinline__ float i2f(int i) { union { int i; float f; } u; u.i = i; return u.f; }
__device__ __forceinline__ int f2i(float f) { union { float f; int i; } u; u.f = f; return u.i; }
template <int C>
__device__ __forceinline__ float dppf(float x) {
  return i2f(__builtin_amdgcn_update_dpp(f2i(x), f2i(x), C, 0xF, 0xF, false));
}
__device__ __forceinline__ float rowmax16(float x) {
  x = fmaxf(x, dppf<0xB1>(x));   // quad_perm [1,0,3,2]
  x = fmaxf(x, dppf<0x4E>(x));   // quad_perm [2,3,0,1]
  x = fmaxf(x, dppf<0x141>(x));  // row_half_mirror
  x = fmaxf(x, dppf<0x140>(x));  // row_mirror
  return x;
}
__device__ __forceinline__ float rowsum16(float x) {
  x += dppf<0xB1>(x);
  x += dppf<0x4E>(x);
  x += dppf<0x141>(x);
  x += dppf<0x140>(x);
  return x;
}

// ---------------------------------------------------------------------------
// conversions
// ---------------------------------------------------------------------------
__global__ __launch_bounds__(256) void cvt_x_kernel(const float* __restrict__ x,
                                                    short* __restrict__ xb) {
  int i = (blockIdx.x * 256 + threadIdx.x) * 4; // over x linear (B,T,D)
  float4 v = *(const float4*)(x + i);
  int d = i & 1023, t = (i >> 10) & 2047, b = i >> 21;
  int h = d >> 6, dd = d & 63;
  short4 o;
  o.x = f2bf(v.x); o.y = f2bf(v.y); o.z = f2bf(v.z); o.w = f2bf(v.w);
  *(short4*)(xb + ((((size_t)b * 16 + h) * T + t) * 64 + dd)) = o;
}

__global__ __launch_bounds__(256) void cvt_w_kernel(
    const float* __restrict__ W_DQ, const float* __restrict__ W_UQ,
    const float* __restrict__ W_DKV, const float* __restrict__ W_UKV,
    const float* __restrict__ W_QR, const float* __restrict__ W_KR,
    const float* __restrict__ W_O, short* __restrict__ wb) {
  int i = blockIdx.x * 256 + threadIdx.x;
  const float* src; int off;
  if      (i < 32768)  { src = W_DQ;  off = 0; }
  else if (i < 65536)  { src = W_UQ;  off = 32768; }
  else if (i < 131072) { src = W_DKV; off = 65536; }
  else if (i < 262144) { src = W_UKV; off = 131072; }
  else if (i < 266240) { src = W_QR;  off = 262144; }
  else if (i < 270336) { src = W_KR;  off = 266240; }
  else                 { src = W_O;   off = 270336; }
  wb[i] = f2bf(src[i - off]);
}

// ---------------------------------------------------------------------------
// proj_q (unchanged from round 2)
// ---------------------------------------------------------------------------
__global__ __launch_bounds__(256) void proj_q_mfma(
    const short* __restrict__ xb, const short* __restrict__ wb,
    const float* __restrict__ qnw, short* __restrict__ qb) {
  __shared__ __attribute__((aligned(16))) short Xs[64 * 64];
  __shared__ __attribute__((aligned(16))) short Wd[64 * 64];
  __shared__ __attribute__((aligned(16))) short Wu[64 * 64];
  __shared__ __attribute__((aligned(16))) short Cs[64 * 64];
  __shared__ __attribute__((aligned(16))) short Qr[64 * 64];

  const int tid = threadIdx.x, lane = tid & 63, w = tid >> 6;
  const int bh = blockIdx.y, t0 = blockIdx.x * 64;
  const int arow = w * 16 + (lane & 15);
  const int koff = (lane >> 4) << 3;

  stage64x64(Xs, xb + ((size_t)bh * T + t0) * 64, 64, tid);

  f4v acc[4];
#pragma unroll
  for (int nt = 0; nt < 4; ++nt) acc[nt] = z4();

  for (int lc = 0; lc < 8; ++lc) {
    const int l0 = lc * 64;
    __syncthreads();
    stage64x64(Wd, wb + OFF_DQ + (size_t)l0 * 64, 64, tid);
    stage64x64(Wu, wb + OFF_UQ + l0, 512, tid);
    __syncthreads();
    f4v cc[4];
#pragma unroll
    for (int nt = 0; nt < 4; ++nt) cc[nt] = z4();
#pragma unroll
    for (int ks = 0; ks < 2; ++ks) {
      bf8v a = ldA128(Xs, arow, ks * 32 + koff);
#pragma unroll
      for (int nt = 0; nt < 4; ++nt) {
        bf8v b = ldA128(Wd, nt * 16 + (lane & 15), ks * 32 + koff);
        cc[nt] = MFMA16(a, b, cc[nt]);
      }
    }
#pragma unroll
    for (int nt = 0; nt < 4; ++nt) scat128(Cs, w * 16, lane, nt, cc[nt]);
#pragma unroll
    for (int ks = 0; ks < 2; ++ks) {
      bf8v a = ldA128(Cs, arow, ks * 32 + koff);
#pragma unroll
      for (int nt = 0; nt < 4; ++nt) {
        bf8v b = ldA128(Wu, nt * 16 + (lane & 15), ks * 32 + koff);
        acc[nt] = MFMA16(a, b, acc[nt]);
      }
    }
  }

  float w4[4];
#pragma unroll
  for (int nt = 0; nt < 4; ++nt) w4[nt] = qnw[nt * 16 + (lane & 15)];
  f4v qn[4];
#pragma unroll
  for (int r = 0; r < 4; ++r) {
    float ss = 0.f;
#pragma unroll
    for (int nt = 0; nt < 4; ++nt) ss += acc[nt][r] * acc[nt][r];
    ss += __shfl_xor(ss, 1, 16); ss += __shfl_xor(ss, 2, 16);
    ss += __shfl_xor(ss, 4, 16); ss += __shfl_xor(ss, 8, 16);
    float inv = rsqrtf(ss * (1.f / 64.f) + EPS);
#pragma unroll
    for (int nt = 0; nt < 4; ++nt) qn[nt][r] = acc[nt][r] * inv * w4[nt];
  }

  __syncthreads();
#pragma unroll
  for (int nt = 0; nt < 4; ++nt) scat128(Cs, w * 16, lane, nt, qn[nt]);
  stage64x64(Wd, wb + OFF_QR, 64, tid);
  __syncthreads();

  f4v qr[4];
#pragma unroll
  for (int nt = 0; nt < 4; ++nt) qr[nt] = z4();
#pragma unroll
  for (int ks = 0; ks < 2; ++ks) {
    bf8v a = ldA128(Cs, arow, ks * 32 + koff);
#pragma unroll
    for (int nt = 0; nt < 4; ++nt) {
      bf8v b = ldA128(Wd, nt * 16 + (lane & 15), ks * 32 + koff);
      qr[nt] = MFMA16(a, b, qr[nt]);
    }
  }
#pragma unroll
  for (int nt = 0; nt < 4; ++nt) scat128(Qr, w * 16, lane, nt, qr[nt]);
  __syncthreads();

  short* qdst = qb + ((size_t)bh * T + t0) * 128;
#pragma unroll
  for (int p = 0; p < 2; ++p) {
    int ci = tid + p * 256;
    int r = ci >> 3, c = (ci & 7) << 3;
    *(bf8v*)(qdst + (size_t)r * 128 + c) =
        *(const bf8v*)((const char*)Cs + swz128(ci * 16));
    *(bf8v*)(qdst + (size_t)r * 128 + 64 + c) =
        *(const bf8v*)((const char*)Qr + swz128(ci * 16));
  }
}

// ---------------------------------------------------------------------------
// proj_kv (unchanged from round 2)
// ---------------------------------------------------------------------------
__global__ __launch_bounds__(256) void proj_kv_mfma(
    const short* __restrict__ xb, const short* __restrict__ wb,
    const float* __restrict__ knw, short* __restrict__ kb, short* __restrict__ vtg) {
  __shared__ __attribute__((aligned(16))) short Xs[64 * 64];
  __shared__ __attribute__((aligned(16))) short Wd[64 * 64];
  __shared__ __attribute__((aligned(16))) short Cs[64 * 64];
  __shared__ __attribute__((aligned(16))) short Wu[128 * 64];
  __shared__ __attribute__((aligned(16))) short Ko[64 * 128];
  __shared__ __attribute__((aligned(16))) short Vt[64 * 64];

  const int tid = threadIdx.x, lane = tid & 63, w = tid >> 6;
  const int bh = blockIdx.y, t0 = blockIdx.x * 64;
  const int arow = w * 16 + (lane & 15);
  const int koff = (lane >> 4) << 3;

  stage64x64(Xs, xb + ((size_t)bh * T + t0) * 64, 64, tid);

  f4v acc[8];
#pragma unroll
  for (int nt = 0; nt < 8; ++nt) acc[nt] = z4();

  for (int lc = 0; lc < 16; ++lc) {
    const int l0 = lc * 64;
    __syncthreads();
    stage64x64(Wd, wb + OFF_DKV + (size_t)l0 * 64, 64, tid);
    stage128x64(Wu, wb + OFF_UKV + l0, 1024, tid);
    __syncthreads();
    f4v cc[4];
#pragma unroll
    for (int nt = 0; nt < 4; ++nt) cc[nt] = z4();
#pragma unroll
    for (int ks = 0; ks < 2; ++ks) {
      bf8v a = ldA128(Xs, arow, ks * 32 + koff);
#pragma unroll
      for (int nt = 0; nt < 4; ++nt) {
        bf8v b = ldA128(Wd, nt * 16 + (lane & 15), ks * 32 + koff);
        cc[nt] = MFMA16(a, b, cc[nt]);
      }
    }
#pragma unroll
    for (int nt = 0; nt < 4; ++nt) scat128(Cs, w * 16, lane, nt, cc[nt]);
#pragma unroll
    for (int ks = 0; ks < 2; ++ks) {
      bf8v a = ldA128(Cs, arow, ks * 32 + koff);
#pragma unroll
      for (int nt = 0; nt < 8; ++nt) {
        bf8v b = ldA128(Wu, nt * 16 + (lane & 15), ks * 32 + koff);
        acc[nt] = MFMA16(a, b, acc[nt]);
      }
    }
  }

  float w4[4];
#pragma unroll
  for (int nt = 0; nt < 4; ++nt) w4[nt] = knw[nt * 16 + (lane & 15)];
#pragma unroll
  for (int r = 0; r < 4; ++r) {
    float ss = 0.f;
#pragma unroll
    for (int nt = 0; nt < 4; ++nt) ss += acc[nt][r] * acc[nt][r];
    ss += __shfl_xor(ss, 1, 16); ss += __shfl_xor(ss, 2, 16);
    ss += __shfl_xor(ss, 4, 16); ss += __shfl_xor(ss, 8, 16);
    float inv = rsqrtf(ss * (1.f / 64.f) + EPS);
#pragma unroll
    for (int nt = 0; nt < 4; ++nt) acc[nt][r] *= inv * w4[nt];
  }
#pragma unroll
  for (int nt = 0; nt < 4; ++nt) scat256(Ko, w * 16, lane, nt * 16 + (lane & 15), acc[nt]);
#pragma unroll
  for (int nt = 0; nt < 4; ++nt) {
    int d = nt * 16 + (lane & 15);
    int tl0 = w * 16 + ((lane >> 4) << 2);
#pragma unroll
    for (int r = 0; r < 4; ++r)
      *(short*)((char*)Vt + swz128(d * 128 + (tl0 + r) * 2)) = f2bf(acc[4 + nt][r]);
  }

  __syncthreads();
  stage64x64(Wd, wb + OFF_KR, 64, tid);
  __syncthreads();
  f4v kr[4];
#pragma unroll
  for (int nt = 0; nt < 4; ++nt) kr[nt] = z4();
#pragma unroll
  for (int ks = 0; ks < 2; ++ks) {
    bf8v a = ldA128(Xs, arow, ks * 32 + koff);
#pragma unroll
    for (int nt = 0; nt < 4; ++nt) {
      bf8v b = ldA128(Wd, nt * 16 + (lane & 15), ks * 32 + koff);
      kr[nt] = MFMA16(a, b, kr[nt]);
    }
  }
#pragma unroll
  for (int nt = 0; nt < 4; ++nt) scat256(Ko, w * 16, lane, 64 + nt * 16 + (lane & 15), kr[nt]);
  __syncthreads();

  short* kdst = kb + ((size_t)bh * T + t0) * 128;
#pragma unroll
  for (int p = 0; p < 4; ++p) {
    int ci = tid + p * 256;
    int r = ci >> 4, c = (ci & 15) << 3;
    *(bf8v*)(kdst + (size_t)r * 128 + c) =
        *(const bf8v*)((const char*)Ko + swz256(ci * 16));
  }
#pragma unroll
  for (int p = 0; p < 2; ++p) {
    int ci = tid + p * 256;
    int d = ci >> 3, c = (ci & 7) << 3;
    *(bf8v*)(vtg + ((size_t)bh * 64 + d) * T + t0 + c) =
        *(const bf8v*)((const char*)Vt + swz128(ci * 16));
  }
}

// ---------------------------------------------------------------------------
// attn v3: paired q-tiles (uniform 33 K-tiles/block), async double-buffered K
// staging via global_load_lds, DPP softmax, V prefetched to regs, XCD-clustered
// bh mapping. grid (16, 32), block 256.
// ---------------------------------------------------------------------------
__global__ __launch_bounds__(256) void attn_mfma(
    const short* __restrict__ qb, const short* __restrict__ kb,
    const short* __restrict__ vtg, const short* __restrict__ wb,
    float* __restrict__ out) {
  __shared__ __attribute__((aligned(16))) short Ks[2][64 * 128]; // logical swz256
  __shared__ __attribute__((aligned(16))) short Ps[64 * 64];     // swz128

  const int tid = threadIdx.x, lane = tid & 63, w = tid >> 6;
  // XCD-clustered (bh, pair) mapping: each XCD owns 4 bh values (KV fits L2)
  const int lin = blockIdx.y * 16 + blockIdx.x; // [0,512)
  const int xcd = lin & 7, slot = lin >> 3;     // slot [0,64)
  const int bh = xcd + 8 * (slot >> 4);
  const int px = slot & 15;
  const int qt_pair[2] = {px, 31 - px};

  const int b = bh >> 4, h = bh & 15;
  const int koff = (lane >> 4) << 3;

  const short* kbh = kb + (size_t)bh * T * 128;
  const short* vbh = vtg + (size_t)bh * 64 * T;

  // stage K-tile jt into Ks[buf]: linear LDS dest, inverse-swizzled global src
  auto stageK = [&](int jt, int buf) {
    const char* src = (const char*)(kbh + jt * 64 * 128);
    char* dst = (char*)&Ks[buf][0];
#pragma unroll
    for (int p = 0; p < 4; ++p) {
      int base = p * 256 + w * 64; // wave-uniform chunk base
      gload_lds16(src + swz256((base + lane) * 16), dst + base * 16);
    }
  };

  const int NTtot = 33; // (qta+1) + (qtb+1)
  int cur = 0, g = 0;
  stageK(0, 0);
  __syncthreads();

  for (int seg = 0; seg < 2; ++seg) {
    const int qt = qt_pair[seg];
    const int t0 = qt * 64;
    const int lrow = w * 16 + ((lane >> 4) << 2);

    bf8v aq[4];
    {
      const short* qsrc = qb + ((size_t)bh * T + t0 + w * 16 + (lane & 15)) * 128;
#pragma unroll
      for (int ks = 0; ks < 4; ++ks) aq[ks] = *(const bf8v*)(qsrc + ks * 32 + koff);
    }

    f4v ctx[4];
    float m[4], l[4];
#pragma unroll
    for (int nt = 0; nt < 4; ++nt) ctx[nt] = z4();
#pragma unroll
    for (int r = 0; r < 4; ++r) { m[r] = -INFINITY; l[r] = 0.f; }

    for (int jt = 0; jt <= qt; ++jt, ++g) {
      // issue next tile's staging first (overlaps with compute below)
      if (g + 1 < NTtot) stageK((jt < qt) ? jt + 1 : 0, cur ^ 1);

      const int j0 = jt * 64;
      // V prefetch to regs (consumed by PV; latency hides under QK+softmax)
      bf8v vb[2][4];
#pragma unroll
      for (int ks = 0; ks < 2; ++ks)
#pragma unroll
        for (int nt = 0; nt < 4; ++nt)
          vb[ks][nt] = *(const bf8v*)(vbh + (size_t)(nt * 16 + (lane & 15)) * T +
                                      j0 + ks * 32 + koff);

      // QK^T
      f4v s[4];
#pragma unroll
      for (int nt = 0; nt < 4; ++nt) s[nt] = z4();
#pragma unroll
      for (int ks = 0; ks < 4; ++ks) {
#pragma unroll
        for (int nt = 0; nt < 4; ++nt) {
          bf8v bk = ldA256(Ks[cur], nt * 16 + (lane & 15), ks * 32 + koff);
          s[nt] = MFMA16(aq[ks], bk, s[nt]);
        }
      }

      // online softmax (DPP row reductions)
      const bool diag = (jt == qt);
#pragma unroll
      for (int r = 0; r < 4; ++r) {
        const int grow = t0 + lrow + r;
        float sv[4];
#pragma unroll
        for (int nt = 0; nt < 4; ++nt) {
          float xv = s[nt][r] * SCALE;
          if (diag && (j0 + nt * 16 + (lane & 15) > grow)) xv = -INFINITY;
          sv[nt] = xv;
        }
        float mx = rowmax16(fmaxf(fmaxf(sv[0], sv[1]), fmaxf(sv[2], sv[3])));
        const float mn  = fmaxf(m[r], mx);
        const float scl = __expf(m[r] - mn);
        float p4[4];
        float rs = 0.f;
#pragma unroll
        for (int nt = 0; nt < 4; ++nt) { p4[nt] = __expf(sv[nt] - mn); rs += p4[nt]; }
        rs = rowsum16(rs);
        l[r] = l[r] * scl + rs; m[r] = mn;
#pragma unroll
        for (int nt = 0; nt < 4; ++nt) {
          ctx[nt][r] *= scl;
          *(short*)((char*)Ps + swz128((lrow + r) * 128 + (nt * 16 + (lane & 15)) * 2)) =
              f2bf(p4[nt]);
        }
      }

      // PV (P rows wave-private in Ps; V from regs)
#pragma unroll
      for (int ks = 0; ks < 2; ++ks) {
        bf8v pa = ldA128(Ps, w * 16 + (lane & 15), ks * 32 + koff);
#pragma unroll
        for (int nt = 0; nt < 4; ++nt) ctx[nt] = MFMA16(pa, vb[ks][nt], ctx[nt]);
      }

      __syncthreads(); // drains staging loads (implicit vmcnt(0)) + barrier
      cur ^= 1;
    }

    // epilogue: ctx/l -> Ps, out = ctx @ W_O^T (W_O B-frags direct from global)
    f4v cn[4];
#pragma unroll
    for (int nt = 0; nt < 4; ++nt) {
#pragma unroll
      for (int r = 0; r < 4; ++r) cn[nt][r] = ctx[nt][r] / l[r];
    }
#pragma unroll
    for (int nt = 0; nt < 4; ++nt) scat128(Ps, w * 16, lane, nt, cn[nt]);

    f4v o[4];
#pragma unroll
    for (int nt = 0; nt < 4; ++nt) o[nt] = z4();
#pragma unroll
    for (int ks = 0; ks < 2; ++ks) {
      bf8v pa = ldA128(Ps, w * 16 + (lane & 15), ks * 32 + koff);
#pragma unroll
      for (int nt = 0; nt < 4; ++nt) {
        bf8v bw = *(const bf8v*)(wb + OFF_O + (size_t)(nt * 16 + (lane & 15)) * 64 +
                                 ks * 32 + koff);
        o[nt] = MFMA16(pa, bw, o[nt]);
      }
    }

    float* obase = out + (size_t)b * T * 1024 + h * 64;
#pragma unroll
    for (int nt = 0; nt < 4; ++nt) {
#pragma unroll
      for (int r = 0; r < 4; ++r)
        obase[(size_t)(t0 + lrow + r) * 1024 + nt * 16 + (lane & 15)] = o[nt][r];
    }
  }
}

} // namespace

extern "C" void kernel_launch(void* const* d_in, const int* in_sizes, int n_in,
                              void* d_out, int out_size, void* d_ws, size_t ws_size,
                              hipStream_t stream) {
  (void)in_sizes; (void)n_in; (void)out_size; (void)ws_size;
  const float* x     = (const float*)d_in[0];
  const float* W_DQ  = (const float*)d_in[1];
  const float* W_UQ  = (const float*)d_in[2];
  const float* W_DKV = (const float*)d_in[3];
  const float* W_UKV = (const float*)d_in[4];
  const float* W_QR  = (const float*)d_in[5];
  const float* W_KR  = (const float*)d_in[6];
  const float* W_O   = (const float*)d_in[7];
  const float* qnw   = (const float*)d_in[8];
  const float* knw   = (const float*)d_in[9];
  float* out = (float*)d_out;

  short* ws = (short*)d_ws;
  short* xb  = ws;                          // 4,194,304
  short* qb  = ws + (size_t)4194304;        // 8,388,608
  short* kb  = ws + (size_t)12582912;       // 8,388,608
  short* vtg = ws + (size_t)20971520;       // 4,194,304
  short* wb  = ws + (size_t)25165824;       // 274,432

  cvt_x_kernel<<<4096, 256, 0, stream>>>(x, xb);
  cvt_w_kernel<<<W_TOTAL / 256, 256, 0, stream>>>(W_DQ, W_UQ, W_DKV, W_UKV,
                                                  W_QR, W_KR, W_O, wb);
  dim3 grid(T / 64, 32);
  proj_q_mfma<<<grid, 256, 0, stream>>>(xb, wb, qnw, qb);
  proj_kv_mfma<<<grid, 256, 0, stream>>>(xb, wb, knw, kb, vtg);
  dim3 agrid(16, 32); // paired q-tiles, uniform work
  attn_mfma<<<agrid, 256, 0, stream>>>(qb, kb, vtg, wb, out);
}